// Round 4
// baseline (1641.083 us; speedup 1.0000x reference)
//
#include <hip/hip_runtime.h>
#include <hip/hip_bf16.h>

#define N_NODES 300000
#define N_EDGES 600000
#define IN_DIMC 64
#define HIDC    128
#define NLAYERS 2
#define BN_EPS  1e-5f
#define INV_SQRT_H 0.08838834764831845f  // 1/sqrt(128)
#define NB_SCAN ((N_NODES + 255) / 256)  // 1172
#define NTILES  (N_NODES / 16)           // 18750 (exact)
#define GEMM_GRID 2048                   // 8 blocks/CU -> up to 32 waves/CU

typedef __bf16 bf16x8 __attribute__((ext_vector_type(8)));
typedef float floatx4 __attribute__((ext_vector_type(4)));

// ---------------------------------------------------------------------------
// Module-static scratch; d_ws holds agg as two bf16 planes (hi|lo), 153.6 MB
// total — same bytes as the old fp32 agg, but pre-split for MFMA fragments.
// ---------------------------------------------------------------------------
__device__ int   g_row_ptr[N_NODES + 1];
__device__ int   g_cursor[N_NODES];
__device__ __align__(8) int2 g_edge[N_EDGES];   // x = src, y = bits(1/(1+len))
__device__ __align__(8) int2 g_ew[N_EDGES];     // per-layer: x = src, y = bits(wt)
__device__ int   g_bsum[NB_SCAN];
__device__ float g_ekey[N_NODES];               // exp(key) per src node
__device__ __align__(16) __hip_bfloat16 g_Win_hi[128 * 64];
__device__ __align__(16) __hip_bfloat16 g_Win_lo[128 * 64];
__device__ __align__(16) __hip_bfloat16 g_Wl_hi[NLAYERS * 128 * 128];
__device__ __align__(16) __hip_bfloat16 g_Wl_lo[NLAYERS * 128 * 128];
__device__ float g_stats[NLAYERS * 2 * HIDC];   // per layer: [sum(128) | sumsq(128)]
__device__ __align__(16) float g_bn_sc[NLAYERS * HIDC];
__device__ __align__(16) float g_bn_sh[NLAYERS * HIDC];

// split fp32 into hi+lo bf16 (combined ~2^-17 relative error)
__device__ inline void split2(float x, __hip_bfloat16& hi, __hip_bfloat16& lo) {
    hi = __float2bfloat16(x);
    lo = __float2bfloat16(x - __bfloat162float(hi));
}

// ---------------------------------------------------------------------------
__global__ void zero_kernel() {
    int i = blockIdx.x * 256 + threadIdx.x;
    if (i < N_NODES) g_cursor[i] = 0;
    if (i < NLAYERS * 2 * HIDC) g_stats[i] = 0.f;
}

// ---------------------------------------------------------------------------
// Weight prep: transpose to [n][k] (MFMA fragments = 8 contiguous k), split.
// ---------------------------------------------------------------------------
__global__ void prep_w_kernel(const float* __restrict__ W_in,
                              const float* __restrict__ Wl)
{
    int id = blockIdx.x * 256 + threadIdx.x;
    if (id < 128 * 64) {
        int n = id >> 6, k = id & 63;
        split2(W_in[k * 128 + n], g_Win_hi[id], g_Win_lo[id]);
    }
    if (id < NLAYERS * 128 * 128) {
        int l = id >> 14, r = id & 16383;
        int n = r >> 7, k = r & 127;
        split2(Wl[l * 16384 + k * 128 + n], g_Wl_hi[id], g_Wl_lo[id]);
    }
}

// ---------------------------------------------------------------------------
// CSR build: hist -> scan -> scatter (packed src + inv-len per edge)
// ---------------------------------------------------------------------------
__global__ void hist_kernel(const int* __restrict__ dst)
{
    int e = blockIdx.x * 256 + threadIdx.x;
    if (e < N_EDGES) atomicAdd(&g_cursor[dst[e]], 1);
}

__global__ void scan1_kernel()
{
    __shared__ int tmp[256];
    int t = threadIdx.x;
    int i = blockIdx.x * 256 + t;
    tmp[t] = (i < N_NODES) ? g_cursor[i] : 0;
    __syncthreads();
    for (int d = 128; d > 0; d >>= 1) {
        if (t < d) tmp[t] += tmp[t + d];
        __syncthreads();
    }
    if (t == 0) g_bsum[blockIdx.x] = tmp[0];
}

__global__ void scan2_kernel()
{
    __shared__ int tmp[256];
    __shared__ int carry;
    int t = threadIdx.x;
    if (t == 0) { carry = 0; g_row_ptr[N_NODES] = N_EDGES; }
    __syncthreads();
    for (int base = 0; base < NB_SCAN; base += 256) {
        int i = base + t;
        int v = (i < NB_SCAN) ? g_bsum[i] : 0;
        tmp[t] = v;
        __syncthreads();
        for (int d = 1; d < 256; d <<= 1) {
            int x = (t >= d) ? tmp[t - d] : 0;
            __syncthreads();
            tmp[t] += x;
            __syncthreads();
        }
        int c = carry;
        if (i < NB_SCAN) g_bsum[i] = c + tmp[t] - v;  // exclusive
        __syncthreads();
        if (t == 0) carry = c + tmp[255];
        __syncthreads();
    }
}

__global__ void scan3_kernel()
{
    __shared__ int tmp[256];
    int t = threadIdx.x;
    int i = blockIdx.x * 256 + t;
    int v = (i < N_NODES) ? g_cursor[i] : 0;
    tmp[t] = v;
    __syncthreads();
    for (int d = 1; d < 256; d <<= 1) {
        int x = (t >= d) ? tmp[t - d] : 0;
        __syncthreads();
        tmp[t] += x;
        __syncthreads();
    }
    int r = g_bsum[blockIdx.x] + tmp[t] - v;
    if (i < N_NODES) { g_row_ptr[i] = r; g_cursor[i] = r; }
}

__global__ void scatter_kernel(const int* __restrict__ src, const int* __restrict__ dst,
                               const float* __restrict__ elen)
{
    int e = blockIdx.x * 256 + threadIdx.x;
    if (e >= N_EDGES) return;
    int d = dst[e];
    int pos = atomicAdd(&g_cursor[d], 1);
    int2 ed;
    ed.x = src[e];
    ed.y = __float_as_int(1.0f / (1.0f + elen[e]));
    g_edge[pos] = ed;
}

// ---------------------------------------------------------------------------
// wt_kernel: per-layer edge weight precompute. Packs {src, wt} so edge_csr's
// inner loop is a 2-level chain (edge -> h row), no dependent ekey load.
// ---------------------------------------------------------------------------
__global__ __launch_bounds__(256) void wt_kernel()
{
    int e = blockIdx.x * 256 + threadIdx.x;
    if (e >= N_EDGES) return;
    int2 ed = g_edge[e];
    int2 ew;
    ew.x = ed.x;
    ew.y = __float_as_int(g_ekey[ed.x] * __int_as_float(ed.y));
    g_ew[e] = ew;
}

// ---------------------------------------------------------------------------
// edge_csr v4: one wave per dst node; lane covers channels {2l, 2l+1}.
// Predicated 4-wide body (up to 4 independent h-row loads in flight).
// Epilogue: BN fold + relu, then split2 -> bf16 hi/lo agg planes.
// ---------------------------------------------------------------------------
__global__ __launch_bounds__(256) void edge_csr_kernel(
    const float* __restrict__ h, __hip_bfloat16* __restrict__ agg_hi,
    __hip_bfloat16* __restrict__ agg_lo, int prev)
{
    int lane = threadIdx.x & 63;
    int n = blockIdx.x * 4 + (threadIdx.x >> 6);
    if (n >= N_NODES) return;
    int beg = g_row_ptr[n], end = g_row_ptr[n + 1];
    float a0 = 0.f, a1 = 0.f, sw = 0.f;
    const float2* h2 = (const float2*)h;
    for (int j = beg; j < end; j += 4) {
        int2 e0 = g_ew[j];
        int2 e1 = (j + 1 < end) ? g_ew[j + 1] : make_int2(e0.x, 0);
        int2 e2 = (j + 2 < end) ? g_ew[j + 2] : make_int2(e0.x, 0);
        int2 e3 = (j + 3 < end) ? g_ew[j + 3] : make_int2(e0.x, 0);
        float w0 = __int_as_float(e0.y);
        float w1 = __int_as_float(e1.y);
        float w2 = __int_as_float(e2.y);
        float w3 = __int_as_float(e3.y);
        float2 x0 = h2[(size_t)e0.x * 64 + lane];
        float2 x1 = h2[(size_t)e1.x * 64 + lane];
        float2 x2 = h2[(size_t)e2.x * 64 + lane];
        float2 x3 = h2[(size_t)e3.x * 64 + lane];
        a0 += w0 * x0.x + w1 * x1.x + w2 * x2.x + w3 * x3.x;
        a1 += w0 * x0.y + w1 * x1.y + w2 * x2.y + w3 * x3.y;
        sw += w0 + w1 + w2 + w3;
    }
    float2 sc = make_float2(1.f, 1.f), sh = make_float2(0.f, 0.f);
    if (prev >= 0) {
        sc = ((const float2*)(g_bn_sc + prev * HIDC))[lane];
        sh = ((const float2*)(g_bn_sh + prev * HIDC))[lane];
    }
    float o0 = fmaxf(sc.x * a0 + sh.x * sw, 0.f);
    float o1 = fmaxf(sc.y * a1 + sh.y * sw, 0.f);
    union { __hip_bfloat16 e[2]; unsigned u; } ph, pl;
    split2(o0, ph.e[0], pl.e[0]);
    split2(o1, ph.e[1], pl.e[1]);
    ((unsigned*)agg_hi)[(size_t)n * 64 + lane] = ph.u;
    ((unsigned*)agg_lo)[(size_t)n * 64 + lane] = pl.u;
}

// ---------------------------------------------------------------------------
// proj: h[64 x 128] = X @ W_in + b via bf16x3 split MFMA; epilogue also emits
// g_ekey[n] = exp(dot(h[n], att_k) / sqrt(H)) for layer 0 (no BN before it).
// ---------------------------------------------------------------------------
__global__ __launch_bounds__(256) void proj_mfma_kernel(
    const float* __restrict__ X, const float* __restrict__ b,
    const float* __restrict__ att_k, float* __restrict__ h)
{
    __shared__ __align__(16) __hip_bfloat16 Ah[64 * 72];
    __shared__ __align__(16) __hip_bfloat16 Al[64 * 72];
    __shared__ __align__(16) __hip_bfloat16 Bh[128 * 72];
    __shared__ __align__(16) __hip_bfloat16 Bl[128 * 72];
    int t = threadIdx.x;
    int nbase = blockIdx.x * 64;

    for (int i = t; i < 1024; i += 256) {            // B: 128 rows x 64 k
        int row = i >> 3, c8 = i & 7;
        *(float4*)((char*)Bh + row * 144 + c8 * 16) =
            *(const float4*)((const char*)g_Win_hi + row * 128 + c8 * 16);
        *(float4*)((char*)Bl + row * 144 + c8 * 16) =
            *(const float4*)((const char*)g_Win_lo + row * 128 + c8 * 16);
    }
    for (int i = t; i < 1024; i += 256) {            // A: 64 rows x 64 k
        int row = i >> 4, c4 = i & 15;
        int n = nbase + row;
        float4 v = make_float4(0.f, 0.f, 0.f, 0.f);
        if (n < N_NODES) v = *(const float4*)(X + (size_t)n * IN_DIMC + c4 * 4);
        union { __hip_bfloat16 e[4]; uint2 u; } ph, pl;
        split2(v.x, ph.e[0], pl.e[0]); split2(v.y, ph.e[1], pl.e[1]);
        split2(v.z, ph.e[2], pl.e[2]); split2(v.w, ph.e[3], pl.e[3]);
        *(uint2*)((char*)Ah + row * 144 + c4 * 8) = ph.u;
        *(uint2*)((char*)Al + row * 144 + c4 * 8) = pl.u;
    }
    __syncthreads();

    int lane = t & 63, w = t >> 6;
    int m16 = lane & 15, quad = lane >> 4;
    floatx4 acc[8];
#pragma unroll
    for (int i = 0; i < 8; ++i) acc[i] = floatx4{0.f, 0.f, 0.f, 0.f};

#pragma unroll
    for (int kk = 0; kk < 64; kk += 32) {
        bf16x8 ah = *(const bf16x8*)((const char*)Ah + (w * 16 + m16) * 144 + (kk + quad * 8) * 2);
        bf16x8 al = *(const bf16x8*)((const char*)Al + (w * 16 + m16) * 144 + (kk + quad * 8) * 2);
#pragma unroll
        for (int nt = 0; nt < 8; ++nt) {
            bf16x8 bh = *(const bf16x8*)((const char*)Bh + (nt * 16 + m16) * 144 + (kk + quad * 8) * 2);
            bf16x8 bl = *(const bf16x8*)((const char*)Bl + (nt * 16 + m16) * 144 + (kk + quad * 8) * 2);
            acc[nt] = __builtin_amdgcn_mfma_f32_16x16x32_bf16(ah, bh, acc[nt], 0, 0, 0);
            acc[nt] = __builtin_amdgcn_mfma_f32_16x16x32_bf16(al, bh, acc[nt], 0, 0, 0);
            acc[nt] = __builtin_amdgcn_mfma_f32_16x16x32_bf16(ah, bl, acc[nt], 0, 0, 0);
        }
    }
    float dotr[4] = {0.f, 0.f, 0.f, 0.f};
#pragma unroll
    for (int nt = 0; nt < 8; ++nt) {
        int ch = nt * 16 + m16;
        float bias = b[ch];
        float ak = att_k[ch];
#pragma unroll
        for (int r = 0; r < 4; ++r) {
            int n = nbase + w * 16 + quad * 4 + r;
            float o = acc[nt][r] + bias;
            if (n < N_NODES) h[(size_t)n * HIDC + ch] = o;
            dotr[r] += ak * o;
        }
    }
#pragma unroll
    for (int r = 0; r < 4; ++r) {
        float p = dotr[r];
        p += __shfl_xor(p, 1); p += __shfl_xor(p, 2);
        p += __shfl_xor(p, 4); p += __shfl_xor(p, 8);
        int n = nbase + w * 16 + quad * 4 + r;
        if (m16 == 0 && n < N_NODES) g_ekey[n] = __expf(p * INV_SQRT_H);
    }
}

// ---------------------------------------------------------------------------
// key_kernel: g_ekey[n] = exp(dot(bn_prev(h[n]), att_k)/sqrt(H)).
// ---------------------------------------------------------------------------
__global__ __launch_bounds__(256) void key_kernel(const float* __restrict__ h,
                                                  const float* __restrict__ att_k,
                                                  int prev)
{
    int t = threadIdx.x;
    int lane = t & 63;
    int half = lane >> 5, sub = lane & 31;
    int n = (blockIdx.x * 4 + (t >> 6)) * 2 + half;
    if (n >= N_NODES) return;
    float4 x = ((const float4*)h)[(size_t)n * 32 + sub];
    float4 sc = ((const float4*)(g_bn_sc + prev * HIDC))[sub];
    float4 sh = ((const float4*)(g_bn_sh + prev * HIDC))[sub];
    float4 ak = ((const float4*)att_k)[sub];
    float p = (sc.x * x.x + sh.x) * ak.x + (sc.y * x.y + sh.y) * ak.y +
              (sc.z * x.z + sh.z) * ak.z + (sc.w * x.w + sh.w) * ak.w;
    p += __shfl_xor(p, 1);  p += __shfl_xor(p, 2);
    p += __shfl_xor(p, 4);  p += __shfl_xor(p, 8);
    p += __shfl_xor(p, 16);
    if (sub == 0) g_ekey[n] = __expf(p * INV_SQRT_H);
}

// ---------------------------------------------------------------------------
// layer_gemm v3: zero LDS, transposed MFMA (D[ch][node]) so each lane owns
// 4 CONSECUTIVE channels of one node -> float4 residual read + store.
// Operand fragments are the same loads as v2 (A/B lane layouts symmetric);
// only the mfma argument order and epilogue mapping change. Grid 2048 fills
// the machine (v2's 768 blocks starved occupancy at 29%).
// ---------------------------------------------------------------------------
__global__ __launch_bounds__(256, 4) void layer_gemm_kernel(
    float* __restrict__ h, const __hip_bfloat16* __restrict__ agg_hi,
    const __hip_bfloat16* __restrict__ agg_lo,
    const float* __restrict__ b, int layer, int prev)
{
    const int t = threadIdx.x;
    const int lane = t & 63, w = t >> 6;
    const int m16 = lane & 15, quad = lane >> 4;

    // W fragments (A-operand): lane m16 = ch row within 16-block, quad = k.
    bf16x8 bh[2][4], blv[2][4];
#pragma unroll
    for (int nt = 0; nt < 2; ++nt) {
        int ch = w * 32 + nt * 16 + m16;
        const __hip_bfloat16* Wh  = g_Wl_hi + layer * 16384 + ch * 128 + quad * 8;
        const __hip_bfloat16* Wl2 = g_Wl_lo + layer * 16384 + ch * 128 + quad * 8;
#pragma unroll
        for (int kk = 0; kk < 4; ++kk) {
            bh[nt][kk]  = *(const bf16x8*)(Wh  + kk * 32);
            blv[nt][kk] = *(const bf16x8*)(Wl2 + kk * 32);
        }
    }
    // epilogue constants: 4 consecutive channels at chb (per nt)
    float4 bias4[2], scp4[2], shp4[2];
#pragma unroll
    for (int nt = 0; nt < 2; ++nt) {
        int chb = w * 32 + nt * 16 + quad * 4;
        bias4[nt] = *(const float4*)(b + chb);
        if (prev >= 0) {
            scp4[nt] = *(const float4*)(g_bn_sc + prev * HIDC + chb);
            shp4[nt] = *(const float4*)(g_bn_sh + prev * HIDC + chb);
        } else {
            scp4[nt] = make_float4(1.f, 1.f, 1.f, 1.f);
            shp4[nt] = make_float4(0.f, 0.f, 0.f, 0.f);
        }
    }
    float sreg[2][4], qreg[2][4];
#pragma unroll
    for (int nt = 0; nt < 2; ++nt)
#pragma unroll
        for (int r = 0; r < 4; ++r) { sreg[nt][r] = 0.f; qreg[nt][r] = 0.f; }

    for (int tile = blockIdx.x; tile < NTILES; tile += gridDim.x) {
        const __hip_bfloat16* ahp = agg_hi + (size_t)(tile * 16 + m16) * HIDC + quad * 8;
        const __hip_bfloat16* alp = agg_lo + (size_t)(tile * 16 + m16) * HIDC + quad * 8;
        floatx4 acc[2];
        acc[0] = floatx4{0.f, 0.f, 0.f, 0.f};
        acc[1] = floatx4{0.f, 0.f, 0.f, 0.f};
#pragma unroll
        for (int kk = 0; kk < 4; ++kk) {
            bf16x8 ah = *(const bf16x8*)(ahp + kk * 32);   // B-operand: agg rows
            bf16x8 al = *(const bf16x8*)(alp + kk * 32);
#pragma unroll
            for (int nt = 0; nt < 2; ++nt) {
                acc[nt] = __builtin_amdgcn_mfma_f32_16x16x32_bf16(bh[nt][kk],  ah, acc[nt], 0, 0, 0);
                acc[nt] = __builtin_amdgcn_mfma_f32_16x16x32_bf16(blv[nt][kk], ah, acc[nt], 0, 0, 0);
                acc[nt] = __builtin_amdgcn_mfma_f32_16x16x32_bf16(bh[nt][kk],  al, acc[nt], 0, 0, 0);
            }
        }
        // D[ch][node]: lane m16 = node, (quad*4 + r) = ch within 16-block
        int node = tile * 16 + m16;
#pragma unroll
        for (int nt = 0; nt < 2; ++nt) {
            int chb = w * 32 + nt * 16 + quad * 4;
            float* hp = h + (size_t)node * HIDC + chb;
            float4 hv = *(const float4*)hp;
            float4 o;
            o.x = scp4[nt].x * hv.x + shp4[nt].x + acc[nt][0] + bias4[nt].x;
            o.y = scp4[nt].y * hv.y + shp4[nt].y + acc[nt][1] + bias4[nt].y;
            o.z = scp4[nt].z * hv.z + shp4[nt].z + acc[nt][2] + bias4[nt].z;
            o.w = scp4[nt].w * hv.w + shp4[nt].w + acc[nt][3] + bias4[nt].w;
            *(float4*)hp = o;
            sreg[nt][0] += o.x; qreg[nt][0] += o.x * o.x;
            sreg[nt][1] += o.y; qreg[nt][1] += o.y * o.y;
            sreg[nt][2] += o.z; qreg[nt][2] += o.z * o.z;
            sreg[nt][3] += o.w; qreg[nt][3] += o.w * o.w;
        }
    }

    // BN stats: reduce over nodes (m16 lanes) per channel
#pragma unroll
    for (int nt = 0; nt < 2; ++nt) {
#pragma unroll
        for (int r = 0; r < 4; ++r) {
            float s = sreg[nt][r], q = qreg[nt][r];
            s += __shfl_xor(s, 1); s += __shfl_xor(s, 2);
            s += __shfl_xor(s, 4); s += __shfl_xor(s, 8);
            q += __shfl_xor(q, 1); q += __shfl_xor(q, 2);
            q += __shfl_xor(q, 4); q += __shfl_xor(q, 8);
            if (m16 == 0) {
                int ch = w * 32 + nt * 16 + quad * 4 + r;
                atomicAdd(&g_stats[layer * 2 * HIDC + ch], s);
                atomicAdd(&g_stats[layer * 2 * HIDC + HIDC + ch], q);
            }
        }
    }
}

// ---------------------------------------------------------------------------
// bn_prep: stats -> scale/shift (1 block, 128 threads)
// ---------------------------------------------------------------------------
__global__ void bn_prep_kernel(const float* __restrict__ gamma,
                               const float* __restrict__ beta, int layer)
{
    int c = threadIdx.x;
    if (c >= HIDC) return;
    const float invN = 1.0f / (float)N_NODES;
    float mean = g_stats[layer * 2 * HIDC + c] * invN;
    float var = g_stats[layer * 2 * HIDC + HIDC + c] * invN - mean * mean;
    float s = gamma[layer * HIDC + c] * rsqrtf(var + BN_EPS);
    g_bn_sc[layer * HIDC + c] = s;
    g_bn_sh[layer * HIDC + c] = beta[layer * HIDC + c] - mean * s;
}

// ---------------------------------------------------------------------------
// bn_apply (final output only): h = sc*h + sh
// ---------------------------------------------------------------------------
__global__ __launch_bounds__(256) void bn_apply_kernel(float* __restrict__ h, int layer)
{
    size_t idx = (size_t)blockIdx.x * 256 + threadIdx.x;  // float4 index
    if (idx >= (size_t)N_NODES * (HIDC / 4)) return;
    int cg = (int)(idx & 31);
    float4 sc = ((const float4*)(g_bn_sc + layer * HIDC))[cg];
    float4 sh = ((const float4*)(g_bn_sh + layer * HIDC))[cg];
    float4 v = ((float4*)h)[idx];
    v.x = sc.x * v.x + sh.x;
    v.y = sc.y * v.y + sh.y;
    v.z = sc.z * v.z + sh.z;
    v.w = sc.w * v.w + sh.w;
    ((float4*)h)[idx] = v;
}

// ---------------------------------------------------------------------------
extern "C" void kernel_launch(void* const* d_in, const int* in_sizes, int n_in,
                              void* d_out, int out_size, void* d_ws, size_t ws_size,
                              hipStream_t stream) {
    (void)in_sizes; (void)n_in; (void)out_size; (void)ws_size;
    const float* node_init = (const float*)d_in[0];
    const int*   eidx      = (const int*)d_in[1];   // [2,E] int32
    const float* elen      = (const float*)d_in[2];
    const float* W_in      = (const float*)d_in[3];
    const float* b_in      = (const float*)d_in[4];
    const float* att_k     = (const float*)d_in[5];
    const float* Wl        = (const float*)d_in[6]; // [2,128,128]
    const float* bl        = (const float*)d_in[7]; // [2,128]
    const float* gamma     = (const float*)d_in[8];
    const float* beta      = (const float*)d_in[9];

    float* h = (float*)d_out;                       // [N,128]
    __hip_bfloat16* agg_hi = (__hip_bfloat16*)d_ws; // [N,128] bf16 hi plane
    __hip_bfloat16* agg_lo = agg_hi + (size_t)N_NODES * HIDC; // lo plane

    const int* src = eidx;
    const int* dst = eidx + N_EDGES;

    zero_kernel<<<NB_SCAN, 256, 0, stream>>>();
    hist_kernel<<<(N_EDGES + 255) / 256, 256, 0, stream>>>(dst);
    scan1_kernel<<<NB_SCAN, 256, 0, stream>>>();
    scan2_kernel<<<1, 256, 0, stream>>>();
    scan3_kernel<<<NB_SCAN, 256, 0, stream>>>();
    scatter_kernel<<<(N_EDGES + 255) / 256, 256, 0, stream>>>(src, dst, elen);
    prep_w_kernel<<<(NLAYERS * 128 * 128 + 255) / 256, 256, 0, stream>>>(W_in, Wl);

    proj_mfma_kernel<<<(N_NODES + 63) / 64, 256, 0, stream>>>(node_init, b_in, att_k, h);

    for (int l = 0; l < NLAYERS; ++l) {
        if (l > 0)
            key_kernel<<<(N_NODES / 2 + 3) / 4, 256, 0, stream>>>(h, att_k, l - 1);
        wt_kernel<<<(N_EDGES + 255) / 256, 256, 0, stream>>>();
        edge_csr_kernel<<<(N_NODES + 3) / 4, 256, 0, stream>>>(h, agg_hi, agg_lo, l - 1);
        layer_gemm_kernel<<<GEMM_GRID, 256, 0, stream>>>(h, agg_hi, agg_lo, bl + (size_t)l * HIDC, l, l - 1);
        bn_prep_kernel<<<1, 128, 0, stream>>>(gamma, beta, l);
    }
    bn_apply_kernel<<<(N_NODES * (HIDC / 4) + 255) / 256, 256, 0, stream>>>(h, NLAYERS - 1);
}

// Round 5
// 889.973 us; speedup vs baseline: 1.8440x; 1.8440x over previous
//
#include <hip/hip_runtime.h>
#include <hip/hip_bf16.h>

#define N_NODES 300000
#define N_EDGES 600000
#define IN_DIMC 64
#define HIDC    128
#define NLAYERS 2
#define BN_EPS  1e-5f
#define INV_SQRT_H 0.08838834764831845f  // 1/sqrt(128)
#define NB_SCAN ((N_NODES + 255) / 256)  // 1172
#define NTILES  (N_NODES / 16)           // 18750 (exact)

typedef __bf16 bf16x8 __attribute__((ext_vector_type(8)));
typedef float floatx4 __attribute__((ext_vector_type(4)));

// ---------------------------------------------------------------------------
// Module-static scratch; d_ws holds agg as two bf16 planes (hi|lo).
// ---------------------------------------------------------------------------
__device__ int   g_row_ptr[N_NODES + 1];
__device__ int   g_cursor[N_NODES];
__device__ __align__(8) int2 g_edge[N_EDGES];   // x = src, y = bits(1/(1+len))
__device__ __align__(8) int2 g_ew[N_EDGES];     // per-layer: x = src, y = bits(wt)
__device__ int   g_bsum[NB_SCAN];
__device__ float g_ekey[N_NODES];               // exp(key) per src node
__device__ __align__(16) __hip_bfloat16 g_Win_hi[128 * 64];
__device__ __align__(16) __hip_bfloat16 g_Win_lo[128 * 64];
__device__ __align__(16) __hip_bfloat16 g_Wl_hi[NLAYERS * 128 * 128];
__device__ __align__(16) __hip_bfloat16 g_Wl_lo[NLAYERS * 128 * 128];
__device__ float g_stats[NLAYERS * 2 * HIDC];   // per layer: [sum(128) | sumsq(128)]
__device__ __align__(16) float g_bn_sc[NLAYERS * HIDC];
__device__ __align__(16) float g_bn_sh[NLAYERS * HIDC];

// split fp32 into hi+lo bf16 (combined ~2^-17 relative error)
__device__ inline void split2(float x, __hip_bfloat16& hi, __hip_bfloat16& lo) {
    hi = __float2bfloat16(x);
    lo = __float2bfloat16(x - __bfloat162float(hi));
}

// ---------------------------------------------------------------------------
__global__ void zero_kernel() {
    int i = blockIdx.x * 256 + threadIdx.x;
    if (i < N_NODES) g_cursor[i] = 0;
    if (i < NLAYERS * 2 * HIDC) g_stats[i] = 0.f;
}

// ---------------------------------------------------------------------------
// Weight prep: transpose to [n][k] (MFMA fragments = 8 contiguous k), split.
// ---------------------------------------------------------------------------
__global__ void prep_w_kernel(const float* __restrict__ W_in,
                              const float* __restrict__ Wl)
{
    int id = blockIdx.x * 256 + threadIdx.x;
    if (id < 128 * 64) {
        int n = id >> 6, k = id & 63;
        split2(W_in[k * 128 + n], g_Win_hi[id], g_Win_lo[id]);
    }
    if (id < NLAYERS * 128 * 128) {
        int l = id >> 14, r = id & 16383;
        int n = r >> 7, k = r & 127;
        split2(Wl[l * 16384 + k * 128 + n], g_Wl_hi[id], g_Wl_lo[id]);
    }
}

// ---------------------------------------------------------------------------
// CSR build: hist -> scan -> scatter (packed src + inv-len per edge)
// ---------------------------------------------------------------------------
__global__ void hist_kernel(const int* __restrict__ dst)
{
    int e = blockIdx.x * 256 + threadIdx.x;
    if (e < N_EDGES) atomicAdd(&g_cursor[dst[e]], 1);
}

__global__ void scan1_kernel()
{
    __shared__ int tmp[256];
    int t = threadIdx.x;
    int i = blockIdx.x * 256 + t;
    tmp[t] = (i < N_NODES) ? g_cursor[i] : 0;
    __syncthreads();
    for (int d = 128; d > 0; d >>= 1) {
        if (t < d) tmp[t] += tmp[t + d];
        __syncthreads();
    }
    if (t == 0) g_bsum[blockIdx.x] = tmp[0];
}

__global__ void scan2_kernel()
{
    __shared__ int tmp[256];
    __shared__ int carry;
    int t = threadIdx.x;
    if (t == 0) { carry = 0; g_row_ptr[N_NODES] = N_EDGES; }
    __syncthreads();
    for (int base = 0; base < NB_SCAN; base += 256) {
        int i = base + t;
        int v = (i < NB_SCAN) ? g_bsum[i] : 0;
        tmp[t] = v;
        __syncthreads();
        for (int d = 1; d < 256; d <<= 1) {
            int x = (t >= d) ? tmp[t - d] : 0;
            __syncthreads();
            tmp[t] += x;
            __syncthreads();
        }
        int c = carry;
        if (i < NB_SCAN) g_bsum[i] = c + tmp[t] - v;  // exclusive
        __syncthreads();
        if (t == 0) carry = c + tmp[255];
        __syncthreads();
    }
}

__global__ void scan3_kernel()
{
    __shared__ int tmp[256];
    int t = threadIdx.x;
    int i = blockIdx.x * 256 + t;
    int v = (i < N_NODES) ? g_cursor[i] : 0;
    tmp[t] = v;
    __syncthreads();
    for (int d = 1; d < 256; d <<= 1) {
        int x = (t >= d) ? tmp[t - d] : 0;
        __syncthreads();
        tmp[t] += x;
        __syncthreads();
    }
    int r = g_bsum[blockIdx.x] + tmp[t] - v;
    if (i < N_NODES) { g_row_ptr[i] = r; g_cursor[i] = r; }
}

__global__ void scatter_kernel(const int* __restrict__ src, const int* __restrict__ dst,
                               const float* __restrict__ elen)
{
    int e = blockIdx.x * 256 + threadIdx.x;
    if (e >= N_EDGES) return;
    int d = dst[e];
    int pos = atomicAdd(&g_cursor[d], 1);
    int2 ed;
    ed.x = src[e];
    ed.y = __float_as_int(1.0f / (1.0f + elen[e]));
    g_edge[pos] = ed;
}

// ---------------------------------------------------------------------------
// wt_kernel: per-layer edge weight precompute. Packs {src, wt} so edge_csr's
// inner loop is a 2-level chain (edge -> h row), no dependent ekey load.
// ---------------------------------------------------------------------------
__global__ __launch_bounds__(256) void wt_kernel()
{
    int e = blockIdx.x * 256 + threadIdx.x;
    if (e >= N_EDGES) return;
    int2 ed = g_edge[e];
    int2 ew;
    ew.x = ed.x;
    ew.y = __float_as_int(g_ekey[ed.x] * __int_as_float(ed.y));
    g_ew[e] = ew;
}

// ---------------------------------------------------------------------------
// edge_csr v4: one wave per dst node; lane covers channels {2l, 2l+1}.
// Predicated 4-wide body (up to 4 independent h-row loads in flight).
// Epilogue: BN fold + relu, then split2 -> bf16 hi/lo agg planes (split VALU
// hides under gather latency; removes it from layer_gemm's loop).
// ---------------------------------------------------------------------------
__global__ __launch_bounds__(256) void edge_csr_kernel(
    const float* __restrict__ h, __hip_bfloat16* __restrict__ agg_hi,
    __hip_bfloat16* __restrict__ agg_lo, int prev)
{
    int lane = threadIdx.x & 63;
    int n = blockIdx.x * 4 + (threadIdx.x >> 6);
    if (n >= N_NODES) return;
    int beg = g_row_ptr[n], end = g_row_ptr[n + 1];
    float a0 = 0.f, a1 = 0.f, sw = 0.f;
    const float2* h2 = (const float2*)h;
    for (int j = beg; j < end; j += 4) {
        int2 e0 = g_ew[j];
        int2 e1 = (j + 1 < end) ? g_ew[j + 1] : make_int2(e0.x, 0);
        int2 e2 = (j + 2 < end) ? g_ew[j + 2] : make_int2(e0.x, 0);
        int2 e3 = (j + 3 < end) ? g_ew[j + 3] : make_int2(e0.x, 0);
        float w0 = __int_as_float(e0.y);
        float w1 = __int_as_float(e1.y);
        float w2 = __int_as_float(e2.y);
        float w3 = __int_as_float(e3.y);
        float2 x0 = h2[(size_t)e0.x * 64 + lane];
        float2 x1 = h2[(size_t)e1.x * 64 + lane];
        float2 x2 = h2[(size_t)e2.x * 64 + lane];
        float2 x3 = h2[(size_t)e3.x * 64 + lane];
        a0 += w0 * x0.x + w1 * x1.x + w2 * x2.x + w3 * x3.x;
        a1 += w0 * x0.y + w1 * x1.y + w2 * x2.y + w3 * x3.y;
        sw += w0 + w1 + w2 + w3;
    }
    float2 sc = make_float2(1.f, 1.f), sh = make_float2(0.f, 0.f);
    if (prev >= 0) {
        sc = ((const float2*)(g_bn_sc + prev * HIDC))[lane];
        sh = ((const float2*)(g_bn_sh + prev * HIDC))[lane];
    }
    float o0 = fmaxf(sc.x * a0 + sh.x * sw, 0.f);
    float o1 = fmaxf(sc.y * a1 + sh.y * sw, 0.f);
    union { __hip_bfloat16 e[2]; unsigned u; } ph, pl;
    split2(o0, ph.e[0], pl.e[0]);
    split2(o1, ph.e[1], pl.e[1]);
    ((unsigned*)agg_hi)[(size_t)n * 64 + lane] = ph.u;
    ((unsigned*)agg_lo)[(size_t)n * 64 + lane] = pl.u;
}

// ---------------------------------------------------------------------------
// proj: h[64 x 128] = X @ W_in + b via bf16x3 split MFMA; epilogue also emits
// g_ekey[n] = exp(dot(h[n], att_k) / sqrt(H)) for layer 0 (no BN before it).
// ---------------------------------------------------------------------------
__global__ __launch_bounds__(256) void proj_mfma_kernel(
    const float* __restrict__ X, const float* __restrict__ b,
    const float* __restrict__ att_k, float* __restrict__ h)
{
    __shared__ __align__(16) __hip_bfloat16 Ah[64 * 72];
    __shared__ __align__(16) __hip_bfloat16 Al[64 * 72];
    __shared__ __align__(16) __hip_bfloat16 Bh[128 * 72];
    __shared__ __align__(16) __hip_bfloat16 Bl[128 * 72];
    int t = threadIdx.x;
    int nbase = blockIdx.x * 64;

    for (int i = t; i < 1024; i += 256) {            // B: 128 rows x 64 k
        int row = i >> 3, c8 = i & 7;
        *(float4*)((char*)Bh + row * 144 + c8 * 16) =
            *(const float4*)((const char*)g_Win_hi + row * 128 + c8 * 16);
        *(float4*)((char*)Bl + row * 144 + c8 * 16) =
            *(const float4*)((const char*)g_Win_lo + row * 128 + c8 * 16);
    }
    for (int i = t; i < 1024; i += 256) {            // A: 64 rows x 64 k
        int row = i >> 4, c4 = i & 15;
        int n = nbase + row;
        float4 v = make_float4(0.f, 0.f, 0.f, 0.f);
        if (n < N_NODES) v = *(const float4*)(X + (size_t)n * IN_DIMC + c4 * 4);
        union { __hip_bfloat16 e[4]; uint2 u; } ph, pl;
        split2(v.x, ph.e[0], pl.e[0]); split2(v.y, ph.e[1], pl.e[1]);
        split2(v.z, ph.e[2], pl.e[2]); split2(v.w, ph.e[3], pl.e[3]);
        *(uint2*)((char*)Ah + row * 144 + c4 * 8) = ph.u;
        *(uint2*)((char*)Al + row * 144 + c4 * 8) = pl.u;
    }
    __syncthreads();

    int lane = t & 63, w = t >> 6;
    int m16 = lane & 15, quad = lane >> 4;
    floatx4 acc[8];
#pragma unroll
    for (int i = 0; i < 8; ++i) acc[i] = floatx4{0.f, 0.f, 0.f, 0.f};

#pragma unroll
    for (int kk = 0; kk < 64; kk += 32) {
        bf16x8 ah = *(const bf16x8*)((const char*)Ah + (w * 16 + m16) * 144 + (kk + quad * 8) * 2);
        bf16x8 al = *(const bf16x8*)((const char*)Al + (w * 16 + m16) * 144 + (kk + quad * 8) * 2);
#pragma unroll
        for (int nt = 0; nt < 8; ++nt) {
            bf16x8 bh = *(const bf16x8*)((const char*)Bh + (nt * 16 + m16) * 144 + (kk + quad * 8) * 2);
            bf16x8 bl = *(const bf16x8*)((const char*)Bl + (nt * 16 + m16) * 144 + (kk + quad * 8) * 2);
            acc[nt] = __builtin_amdgcn_mfma_f32_16x16x32_bf16(ah, bh, acc[nt], 0, 0, 0);
            acc[nt] = __builtin_amdgcn_mfma_f32_16x16x32_bf16(al, bh, acc[nt], 0, 0, 0);
            acc[nt] = __builtin_amdgcn_mfma_f32_16x16x32_bf16(ah, bl, acc[nt], 0, 0, 0);
        }
    }
    float dotr[4] = {0.f, 0.f, 0.f, 0.f};
#pragma unroll
    for (int nt = 0; nt < 8; ++nt) {
        int ch = nt * 16 + m16;
        float bias = b[ch];
        float ak = att_k[ch];
#pragma unroll
        for (int r = 0; r < 4; ++r) {
            int n = nbase + w * 16 + quad * 4 + r;
            float o = acc[nt][r] + bias;
            if (n < N_NODES) h[(size_t)n * HIDC + ch] = o;
            dotr[r] += ak * o;
        }
    }
#pragma unroll
    for (int r = 0; r < 4; ++r) {
        float p = dotr[r];
        p += __shfl_xor(p, 1); p += __shfl_xor(p, 2);
        p += __shfl_xor(p, 4); p += __shfl_xor(p, 8);
        int n = nbase + w * 16 + quad * 4 + r;
        if (m16 == 0 && n < N_NODES) g_ekey[n] = __expf(p * INV_SQRT_H);
    }
}

// ---------------------------------------------------------------------------
// key_kernel: g_ekey[n] = exp(dot(bn_prev(h[n]), att_k)/sqrt(H)).
// ---------------------------------------------------------------------------
__global__ __launch_bounds__(256) void key_kernel(const float* __restrict__ h,
                                                  const float* __restrict__ att_k,
                                                  int prev)
{
    int t = threadIdx.x;
    int lane = t & 63;
    int half = lane >> 5, sub = lane & 31;
    int n = (blockIdx.x * 4 + (t >> 6)) * 2 + half;
    if (n >= N_NODES) return;
    float4 x = ((const float4*)h)[(size_t)n * 32 + sub];
    float4 sc = ((const float4*)(g_bn_sc + prev * HIDC))[sub];
    float4 sh = ((const float4*)(g_bn_sh + prev * HIDC))[sub];
    float4 ak = ((const float4*)att_k)[sub];
    float p = (sc.x * x.x + sh.x) * ak.x + (sc.y * x.y + sh.y) * ak.y +
              (sc.z * x.z + sh.z) * ak.z + (sc.w * x.w + sh.w) * ak.w;
    p += __shfl_xor(p, 1);  p += __shfl_xor(p, 2);
    p += __shfl_xor(p, 4);  p += __shfl_xor(p, 8);
    p += __shfl_xor(p, 16);
    if (sub == 0) g_ekey[n] = __expf(p * INV_SQRT_H);
}

// ---------------------------------------------------------------------------
// layer_gemm (R2 structure + pre-split A): stage B (hi+lo) in LDS once;
// waves grid-stride over 16-node tiles; A fragments load directly as bf16x8
// from the pre-split agg planes (no split2 in loop). Epilogue applies bn_prev
// to residual, accumulates BN stats in registers -> LDS -> one atomic pass.
// ---------------------------------------------------------------------------
__global__ __launch_bounds__(256) void layer_gemm_kernel(
    float* __restrict__ h, const __hip_bfloat16* __restrict__ agg_hi,
    const __hip_bfloat16* __restrict__ agg_lo,
    const float* __restrict__ b, int layer, int prev)
{
    __shared__ __align__(16) __hip_bfloat16 Bh[128 * 136];
    __shared__ __align__(16) __hip_bfloat16 Bl[128 * 136];
    __shared__ float red[256];
    int t = threadIdx.x;
    const __hip_bfloat16* Wh = g_Wl_hi + layer * 16384;
    const __hip_bfloat16* Wlo = g_Wl_lo + layer * 16384;
    red[t] = 0.f;

    for (int i = t; i < 2048; i += 256) {      // B: [n=128][k=128], stride 272B
        int row = i >> 4, c8 = i & 15;
        *(float4*)((char*)Bh + row * 272 + c8 * 16) =
            *(const float4*)((const char*)Wh + row * 256 + c8 * 16);
        *(float4*)((char*)Bl + row * 272 + c8 * 16) =
            *(const float4*)((const char*)Wlo + row * 256 + c8 * 16);
    }
    __syncthreads();

    const int lane = t & 63, w = t >> 6;
    const int m16 = lane & 15, quad = lane >> 4;
    const int wid = blockIdx.x * 4 + w;
    const int nwaves = gridDim.x * 4;

    float bias[8], scp[8], shp[8];
#pragma unroll
    for (int nt = 0; nt < 8; ++nt) {
        int ch = nt * 16 + m16;
        bias[nt] = b[ch];
        scp[nt] = (prev >= 0) ? g_bn_sc[prev * HIDC + ch] : 1.f;
        shp[nt] = (prev >= 0) ? g_bn_sh[prev * HIDC + ch] : 0.f;
    }
    float sreg[8], qreg[8];
#pragma unroll
    for (int nt = 0; nt < 8; ++nt) { sreg[nt] = 0.f; qreg[nt] = 0.f; }

    for (int tile = wid; tile < NTILES; tile += nwaves) {
        const __hip_bfloat16* ahp = agg_hi + (size_t)(tile * 16 + m16) * HIDC + quad * 8;
        const __hip_bfloat16* alp = agg_lo + (size_t)(tile * 16 + m16) * HIDC + quad * 8;
        floatx4 acc[8];
#pragma unroll
        for (int i = 0; i < 8; ++i) acc[i] = floatx4{0.f, 0.f, 0.f, 0.f};

#pragma unroll
        for (int kk = 0; kk < 4; ++kk) {
            bf16x8 ah = *(const bf16x8*)(ahp + kk * 32);
            bf16x8 al = *(const bf16x8*)(alp + kk * 32);
#pragma unroll
            for (int nt = 0; nt < 8; ++nt) {
                bf16x8 bh = *(const bf16x8*)((const char*)Bh + (nt * 16 + m16) * 272 + (kk * 32 + quad * 8) * 2);
                bf16x8 bl = *(const bf16x8*)((const char*)Bl + (nt * 16 + m16) * 272 + (kk * 32 + quad * 8) * 2);
                acc[nt] = __builtin_amdgcn_mfma_f32_16x16x32_bf16(ah, bh, acc[nt], 0, 0, 0);
                acc[nt] = __builtin_amdgcn_mfma_f32_16x16x32_bf16(al, bh, acc[nt], 0, 0, 0);
                acc[nt] = __builtin_amdgcn_mfma_f32_16x16x32_bf16(ah, bl, acc[nt], 0, 0, 0);
            }
        }
        int node0 = tile * 16 + quad * 4;
#pragma unroll
        for (int nt = 0; nt < 8; ++nt) {
            int ch = nt * 16 + m16;
#pragma unroll
            for (int r = 0; r < 4; ++r) {
                float* hp = h + (size_t)(node0 + r) * HIDC + ch;
                float o = scp[nt] * (*hp) + shp[nt] + acc[nt][r] + bias[nt];
                *hp = o;
                sreg[nt] += o;
                qreg[nt] += o * o;
            }
        }
    }

#pragma unroll
    for (int nt = 0; nt < 8; ++nt) {
        float s = sreg[nt], q = qreg[nt];
        s += __shfl_xor(s, 16); s += __shfl_xor(s, 32);
        q += __shfl_xor(q, 16); q += __shfl_xor(q, 32);
        if (quad == 0) {
            atomicAdd(&red[nt * 16 + m16], s);
            atomicAdd(&red[HIDC + nt * 16 + m16], q);
        }
    }
    __syncthreads();
    atomicAdd(&g_stats[layer * 2 * HIDC + t], red[t]);
}

// ---------------------------------------------------------------------------
// bn_prep: stats -> scale/shift (1 block, 128 threads)
// ---------------------------------------------------------------------------
__global__ void bn_prep_kernel(const float* __restrict__ gamma,
                               const float* __restrict__ beta, int layer)
{
    int c = threadIdx.x;
    if (c >= HIDC) return;
    const float invN = 1.0f / (float)N_NODES;
    float mean = g_stats[layer * 2 * HIDC + c] * invN;
    float var = g_stats[layer * 2 * HIDC + HIDC + c] * invN - mean * mean;
    float s = gamma[layer * HIDC + c] * rsqrtf(var + BN_EPS);
    g_bn_sc[layer * HIDC + c] = s;
    g_bn_sh[layer * HIDC + c] = beta[layer * HIDC + c] - mean * s;
}

// ---------------------------------------------------------------------------
// bn_apply (final output only): h = sc*h + sh
// ---------------------------------------------------------------------------
__global__ __launch_bounds__(256) void bn_apply_kernel(float* __restrict__ h, int layer)
{
    size_t idx = (size_t)blockIdx.x * 256 + threadIdx.x;  // float4 index
    if (idx >= (size_t)N_NODES * (HIDC / 4)) return;
    int cg = (int)(idx & 31);
    float4 sc = ((const float4*)(g_bn_sc + layer * HIDC))[cg];
    float4 sh = ((const float4*)(g_bn_sh + layer * HIDC))[cg];
    float4 v = ((float4*)h)[idx];
    v.x = sc.x * v.x + sh.x;
    v.y = sc.y * v.y + sh.y;
    v.z = sc.z * v.z + sh.z;
    v.w = sc.w * v.w + sh.w;
    ((float4*)h)[idx] = v;
}

// ---------------------------------------------------------------------------
extern "C" void kernel_launch(void* const* d_in, const int* in_sizes, int n_in,
                              void* d_out, int out_size, void* d_ws, size_t ws_size,
                              hipStream_t stream) {
    (void)in_sizes; (void)n_in; (void)out_size; (void)ws_size;
    const float* node_init = (const float*)d_in[0];
    const int*   eidx      = (const int*)d_in[1];   // [2,E] int32
    const float* elen      = (const float*)d_in[2];
    const float* W_in      = (const float*)d_in[3];
    const float* b_in      = (const float*)d_in[4];
    const float* att_k     = (const float*)d_in[5];
    const float* Wl        = (const float*)d_in[6]; // [2,128,128]
    const float* bl        = (const float*)d_in[7]; // [2,128]
    const float* gamma     = (const float*)d_in[8];
    const float* beta      = (const float*)d_in[9];

    float* h = (float*)d_out;                       // [N,128]
    __hip_bfloat16* agg_hi = (__hip_bfloat16*)d_ws; // [N,128] bf16 hi plane
    __hip_bfloat16* agg_lo = agg_hi + (size_t)N_NODES * HIDC; // lo plane

    const int* src = eidx;
    const int* dst = eidx + N_EDGES;

    zero_kernel<<<NB_SCAN, 256, 0, stream>>>();
    hist_kernel<<<(N_EDGES + 255) / 256, 256, 0, stream>>>(dst);
    scan1_kernel<<<NB_SCAN, 256, 0, stream>>>();
    scan2_kernel<<<1, 256, 0, stream>>>();
    scan3_kernel<<<NB_SCAN, 256, 0, stream>>>();
    scatter_kernel<<<(N_EDGES + 255) / 256, 256, 0, stream>>>(src, dst, elen);
    prep_w_kernel<<<(NLAYERS * 128 * 128 + 255) / 256, 256, 0, stream>>>(W_in, Wl);

    proj_mfma_kernel<<<(N_NODES + 63) / 64, 256, 0, stream>>>(node_init, b_in, att_k, h);

    for (int l = 0; l < NLAYERS; ++l) {
        if (l > 0)
            key_kernel<<<(N_NODES / 2 + 3) / 4, 256, 0, stream>>>(h, att_k, l - 1);
        wt_kernel<<<(N_EDGES + 255) / 256, 256, 0, stream>>>();
        edge_csr_kernel<<<(N_NODES + 3) / 4, 256, 0, stream>>>(h, agg_hi, agg_lo, l - 1);
        layer_gemm_kernel<<<512, 256, 0, stream>>>(h, agg_hi, agg_lo, bl + (size_t)l * HIDC, l, l - 1);
        bn_prep_kernel<<<1, 128, 0, stream>>>(gamma, beta, l);
    }
    bn_apply_kernel<<<(N_NODES * (HIDC / 4) + 255) / 256, 256, 0, stream>>>(h, NLAYERS - 1);
}

// Round 7
// 832.076 us; speedup vs baseline: 1.9723x; 1.0696x over previous
//
#include <hip/hip_runtime.h>
#include <hip/hip_bf16.h>

#define N_NODES 300000
#define N_EDGES 600000
#define IN_DIMC 64
#define HIDC    128
#define NLAYERS 2
#define BN_EPS  1e-5f
#define INV_SQRT_H 0.08838834764831845f  // 1/sqrt(128)
#define NB_SCAN ((N_NODES + 255) / 256)  // 1172
#define NTILES  (N_NODES / 16)           // 18750 (exact)

typedef __bf16 bf16x8 __attribute__((ext_vector_type(8)));
typedef float floatx4 __attribute__((ext_vector_type(4)));

// ---------------------------------------------------------------------------
// Module-static scratch; d_ws holds agg as two bf16 planes (hi|lo).
// ---------------------------------------------------------------------------
__device__ int   g_row_ptr[N_NODES + 1];
__device__ int   g_cursor[N_NODES];
__device__ __align__(8) int2 g_edge[N_EDGES];   // x = src, y = bits(1/(1+len))
__device__ __align__(8) int2 g_ew[N_EDGES];     // per-layer: x = src, y = bits(wt)
__device__ int   g_bsum[NB_SCAN];
__device__ float g_ekey[N_NODES];               // exp(key) per src node
__device__ __align__(16) __hip_bfloat16 g_Win_hi[128 * 64];
__device__ __align__(16) __hip_bfloat16 g_Win_lo[128 * 64];
__device__ __align__(16) __hip_bfloat16 g_Wl_hi[NLAYERS * 128 * 128];
__device__ __align__(16) __hip_bfloat16 g_Wl_lo[NLAYERS * 128 * 128];
__device__ float g_stats[NLAYERS * 2 * HIDC];   // per layer: [sum(128) | sumsq(128)]
__device__ __align__(16) float g_bn_sc[NLAYERS * HIDC];
__device__ __align__(16) float g_bn_sh[NLAYERS * HIDC];

// split fp32 into hi+lo bf16 (combined ~2^-17 relative error)
__device__ inline void split2(float x, __hip_bfloat16& hi, __hip_bfloat16& lo) {
    hi = __float2bfloat16(x);
    lo = __float2bfloat16(x - __bfloat162float(hi));
}

// ---------------------------------------------------------------------------
__global__ void zero_kernel() {
    int i = blockIdx.x * 256 + threadIdx.x;
    if (i < N_NODES) g_cursor[i] = 0;
    if (i < NLAYERS * 2 * HIDC) g_stats[i] = 0.f;
}

// ---------------------------------------------------------------------------
// Weight prep: transpose to [n][k] (MFMA fragments = 8 contiguous k), split.
// ---------------------------------------------------------------------------
__global__ void prep_w_kernel(const float* __restrict__ W_in,
                              const float* __restrict__ Wl)
{
    int id = blockIdx.x * 256 + threadIdx.x;
    if (id < 128 * 64) {
        int n = id >> 6, k = id & 63;
        split2(W_in[k * 128 + n], g_Win_hi[id], g_Win_lo[id]);
    }
    if (id < NLAYERS * 128 * 128) {
        int l = id >> 14, r = id & 16383;
        int n = r >> 7, k = r & 127;
        split2(Wl[l * 16384 + k * 128 + n], g_Wl_hi[id], g_Wl_lo[id]);
    }
}

// ---------------------------------------------------------------------------
// CSR build: hist -> scan -> scatter (packed src + inv-len per edge)
// ---------------------------------------------------------------------------
__global__ void hist_kernel(const int* __restrict__ dst)
{
    int e = blockIdx.x * 256 + threadIdx.x;
    if (e < N_EDGES) atomicAdd(&g_cursor[dst[e]], 1);
}

__global__ void scan1_kernel()
{
    __shared__ int tmp[256];
    int t = threadIdx.x;
    int i = blockIdx.x * 256 + t;
    tmp[t] = (i < N_NODES) ? g_cursor[i] : 0;
    __syncthreads();
    for (int d = 128; d > 0; d >>= 1) {
        if (t < d) tmp[t] += tmp[t + d];
        __syncthreads();
    }
    if (t == 0) g_bsum[blockIdx.x] = tmp[0];
}

__global__ void scan2_kernel()
{
    __shared__ int tmp[256];
    __shared__ int carry;
    int t = threadIdx.x;
    if (t == 0) { carry = 0; g_row_ptr[N_NODES] = N_EDGES; }
    __syncthreads();
    for (int base = 0; base < NB_SCAN; base += 256) {
        int i = base + t;
        int v = (i < NB_SCAN) ? g_bsum[i] : 0;
        tmp[t] = v;
        __syncthreads();
        for (int d = 1; d < 256; d <<= 1) {
            int x = (t >= d) ? tmp[t - d] : 0;
            __syncthreads();
            tmp[t] += x;
            __syncthreads();
        }
        int c = carry;
        if (i < NB_SCAN) g_bsum[i] = c + tmp[t] - v;  // exclusive
        __syncthreads();
        if (t == 0) carry = c + tmp[255];
        __syncthreads();
    }
}

__global__ void scan3_kernel()
{
    __shared__ int tmp[256];
    int t = threadIdx.x;
    int i = blockIdx.x * 256 + t;
    int v = (i < N_NODES) ? g_cursor[i] : 0;
    tmp[t] = v;
    __syncthreads();
    for (int d = 1; d < 256; d <<= 1) {
        int x = (t >= d) ? tmp[t - d] : 0;
        __syncthreads();
        tmp[t] += x;
        __syncthreads();
    }
    int r = g_bsum[blockIdx.x] + tmp[t] - v;
    if (i < N_NODES) { g_row_ptr[i] = r; g_cursor[i] = r; }
}

// scatter v2: runs AFTER proj (ekey for layer 0 is known) -> emits both
// g_edge (src + inv_len, for layer-1 wt) and g_ew (src + wt) directly,
// deleting the layer-0 wt_kernel pass.
__global__ void scatter_kernel(const int* __restrict__ src, const int* __restrict__ dst,
                               const float* __restrict__ elen)
{
    int e = blockIdx.x * 256 + threadIdx.x;
    if (e >= N_EDGES) return;
    int d = dst[e];
    int s = src[e];
    int pos = atomicAdd(&g_cursor[d], 1);
    float il = 1.0f / (1.0f + elen[e]);
    int2 ed;
    ed.x = s;
    ed.y = __float_as_int(il);
    g_edge[pos] = ed;
    int2 ew;
    ew.x = s;
    ew.y = __float_as_int(g_ekey[s] * il);
    g_ew[pos] = ew;
}

// ---------------------------------------------------------------------------
// wt_kernel (layer 1 only): per-edge weight precompute from fresh ekey.
// ---------------------------------------------------------------------------
__global__ __launch_bounds__(256) void wt_kernel()
{
    int e = blockIdx.x * 256 + threadIdx.x;
    if (e >= N_EDGES) return;
    int2 ed = g_edge[e];
    int2 ew;
    ew.x = ed.x;
    ew.y = __float_as_int(g_ekey[ed.x] * __int_as_float(ed.y));
    g_ew[e] = ew;
}

// ---------------------------------------------------------------------------
// edge_csr v5: TWO nodes per wave; half-wave (32 lanes x float4) per node.
// Halves per-byte instruction count vs v4 (float2 x 64 lanes) and removes
// dummy loads (2-wide loop, deg~2 issues exactly its real rows). Two
// independent chains per wave keep 4 rows in flight. Epilogue: BN fold +
// relu + split2 -> bf16 hi/lo planes, uint2 stores.
// ---------------------------------------------------------------------------
__global__ __launch_bounds__(256) void edge_csr_kernel(
    const float* __restrict__ h, __hip_bfloat16* __restrict__ agg_hi,
    __hip_bfloat16* __restrict__ agg_lo, int prev)
{
    int t = threadIdx.x;
    int lane = t & 63;
    int half = lane >> 5, sub = lane & 31;
    int n = (blockIdx.x * 4 + (t >> 6)) * 2 + half;
    if (n >= N_NODES) return;
    int beg = g_row_ptr[n], end = g_row_ptr[n + 1];
    float ax = 0.f, ay = 0.f, az = 0.f, aw = 0.f, sw = 0.f;
    const float4* h4 = (const float4*)h;
    for (int j = beg; j < end; j += 2) {
        int2 e0 = g_ew[j];
        int2 e1 = (j + 1 < end) ? g_ew[j + 1] : make_int2(e0.x, 0);
        float w0 = __int_as_float(e0.y);
        float w1 = __int_as_float(e1.y);
        float4 x0 = h4[(size_t)e0.x * 32 + sub];
        float4 x1 = h4[(size_t)e1.x * 32 + sub];
        ax += w0 * x0.x + w1 * x1.x;
        ay += w0 * x0.y + w1 * x1.y;
        az += w0 * x0.z + w1 * x1.z;
        aw += w0 * x0.w + w1 * x1.w;
        sw += w0 + w1;
    }
    float4 sc = make_float4(1.f, 1.f, 1.f, 1.f);
    float4 sh = make_float4(0.f, 0.f, 0.f, 0.f);
    if (prev >= 0) {
        sc = ((const float4*)(g_bn_sc + prev * HIDC))[sub];
        sh = ((const float4*)(g_bn_sh + prev * HIDC))[sub];
    }
    float o0 = fmaxf(sc.x * ax + sh.x * sw, 0.f);
    float o1 = fmaxf(sc.y * ay + sh.y * sw, 0.f);
    float o2 = fmaxf(sc.z * az + sh.z * sw, 0.f);
    float o3 = fmaxf(sc.w * aw + sh.w * sw, 0.f);
    union { __hip_bfloat16 e[4]; uint2 u; } ph, pl;
    split2(o0, ph.e[0], pl.e[0]);
    split2(o1, ph.e[1], pl.e[1]);
    split2(o2, ph.e[2], pl.e[2]);
    split2(o3, ph.e[3], pl.e[3]);
    ((uint2*)agg_hi)[(size_t)n * 32 + sub] = ph.u;
    ((uint2*)agg_lo)[(size_t)n * 32 + sub] = pl.u;
}

// ---------------------------------------------------------------------------
// proj: h[64 x 128] = X @ W_in + b via bf16x3 split MFMA; epilogue also emits
// g_ekey[n] = exp(dot(h[n], att_k) / sqrt(H)) for layer 0 (no BN before it).
// ---------------------------------------------------------------------------
__global__ __launch_bounds__(256) void proj_mfma_kernel(
    const float* __restrict__ X, const float* __restrict__ b,
    const float* __restrict__ att_k, float* __restrict__ h)
{
    __shared__ __align__(16) __hip_bfloat16 Ah[64 * 72];
    __shared__ __align__(16) __hip_bfloat16 Al[64 * 72];
    __shared__ __align__(16) __hip_bfloat16 Bh[128 * 72];
    __shared__ __align__(16) __hip_bfloat16 Bl[128 * 72];
    int t = threadIdx.x;
    int nbase = blockIdx.x * 64;

    for (int i = t; i < 1024; i += 256) {            // B: 128 rows x 64 k
        int row = i >> 3, c8 = i & 7;
        *(float4*)((char*)Bh + row * 144 + c8 * 16) =
            *(const float4*)((const char*)g_Win_hi + row * 128 + c8 * 16);
        *(float4*)((char*)Bl + row * 144 + c8 * 16) =
            *(const float4*)((const char*)g_Win_lo + row * 128 + c8 * 16);
    }
    for (int i = t; i < 1024; i += 256) {            // A: 64 rows x 64 k
        int row = i >> 4, c4 = i & 15;
        int n = nbase + row;
        float4 v = make_float4(0.f, 0.f, 0.f, 0.f);
        if (n < N_NODES) v = *(const float4*)(X + (size_t)n * IN_DIMC + c4 * 4);
        union { __hip_bfloat16 e[4]; uint2 u; } ph, pl;
        split2(v.x, ph.e[0], pl.e[0]); split2(v.y, ph.e[1], pl.e[1]);
        split2(v.z, ph.e[2], pl.e[2]); split2(v.w, ph.e[3], pl.e[3]);
        *(uint2*)((char*)Ah + row * 144 + c4 * 8) = ph.u;
        *(uint2*)((char*)Al + row * 144 + c4 * 8) = pl.u;
    }
    __syncthreads();

    int lane = t & 63, w = t >> 6;
    int m16 = lane & 15, quad = lane >> 4;
    floatx4 acc[8];
#pragma unroll
    for (int i = 0; i < 8; ++i) acc[i] = floatx4{0.f, 0.f, 0.f, 0.f};

#pragma unroll
    for (int kk = 0; kk < 64; kk += 32) {
        bf16x8 ah = *(const bf16x8*)((const char*)Ah + (w * 16 + m16) * 144 + (kk + quad * 8) * 2);
        bf16x8 al = *(const bf16x8*)((const char*)Al + (w * 16 + m16) * 144 + (kk + quad * 8) * 2);
#pragma unroll
        for (int nt = 0; nt < 8; ++nt) {
            bf16x8 bh = *(const bf16x8*)((const char*)Bh + (nt * 16 + m16) * 144 + (kk + quad * 8) * 2);
            bf16x8 bl = *(const bf16x8*)((const char*)Bl + (nt * 16 + m16) * 144 + (kk + quad * 8) * 2);
            acc[nt] = __builtin_amdgcn_mfma_f32_16x16x32_bf16(ah, bh, acc[nt], 0, 0, 0);
            acc[nt] = __builtin_amdgcn_mfma_f32_16x16x32_bf16(al, bh, acc[nt], 0, 0, 0);
            acc[nt] = __builtin_amdgcn_mfma_f32_16x16x32_bf16(ah, bl, acc[nt], 0, 0, 0);
        }
    }
    float dotr[4] = {0.f, 0.f, 0.f, 0.f};
#pragma unroll
    for (int nt = 0; nt < 8; ++nt) {
        int ch = nt * 16 + m16;
        float bias = b[ch];
        float ak = att_k[ch];
#pragma unroll
        for (int r = 0; r < 4; ++r) {
            int n = nbase + w * 16 + quad * 4 + r;
            float o = acc[nt][r] + bias;
            if (n < N_NODES) h[(size_t)n * HIDC + ch] = o;
            dotr[r] += ak * o;
        }
    }
#pragma unroll
    for (int r = 0; r < 4; ++r) {
        float p = dotr[r];
        p += __shfl_xor(p, 1); p += __shfl_xor(p, 2);
        p += __shfl_xor(p, 4); p += __shfl_xor(p, 8);
        int n = nbase + w * 16 + quad * 4 + r;
        if (m16 == 0 && n < N_NODES) g_ekey[n] = __expf(p * INV_SQRT_H);
    }
}

// ---------------------------------------------------------------------------
// key_kernel: g_ekey[n] = exp(dot(bn_prev(h[n]), att_k)/sqrt(H)).
// ---------------------------------------------------------------------------
__global__ __launch_bounds__(256) void key_kernel(const float* __restrict__ h,
                                                  const float* __restrict__ att_k,
                                                  int prev)
{
    int t = threadIdx.x;
    int lane = t & 63;
    int half = lane >> 5, sub = lane & 31;
    int n = (blockIdx.x * 4 + (t >> 6)) * 2 + half;
    if (n >= N_NODES) return;
    float4 x = ((const float4*)h)[(size_t)n * 32 + sub];
    float4 sc = ((const float4*)(g_bn_sc + prev * HIDC))[sub];
    float4 sh = ((const float4*)(g_bn_sh + prev * HIDC))[sub];
    float4 ak = ((const float4*)att_k)[sub];
    float p = (sc.x * x.x + sh.x) * ak.x + (sc.y * x.y + sh.y) * ak.y +
              (sc.z * x.z + sh.z) * ak.z + (sc.w * x.w + sh.w) * ak.w;
    p += __shfl_xor(p, 1);  p += __shfl_xor(p, 2);
    p += __shfl_xor(p, 4);  p += __shfl_xor(p, 8);
    p += __shfl_xor(p, 16);
    if (sub == 0) g_ekey[n] = __expf(p * INV_SQRT_H);
}

// ---------------------------------------------------------------------------
// layer_gemm (R2 structure + pre-split A): stage B (hi+lo) in LDS once;
// waves grid-stride over 16-node tiles; A fragments load directly as bf16x8
// from the pre-split agg planes (no split2 in loop). Epilogue applies bn_prev
// to residual, accumulates BN stats in registers -> LDS -> one atomic pass.
// ---------------------------------------------------------------------------
__global__ __launch_bounds__(256) void layer_gemm_kernel(
    float* __restrict__ h, const __hip_bfloat16* __restrict__ agg_hi,
    const __hip_bfloat16* __restrict__ agg_lo,
    const float* __restrict__ b, int layer, int prev)
{
    __shared__ __align__(16) __hip_bfloat16 Bh[128 * 136];
    __shared__ __align__(16) __hip_bfloat16 Bl[128 * 136];
    __shared__ float red[256];
    int t = threadIdx.x;
    const __hip_bfloat16* Wh = g_Wl_hi + layer * 16384;
    const __hip_bfloat16* Wlo = g_Wl_lo + layer * 16384;
    red[t] = 0.f;

    for (int i = t; i < 2048; i += 256) {      // B: [n=128][k=128], stride 272B
        int row = i >> 4, c8 = i & 15;
        *(float4*)((char*)Bh + row * 272 + c8 * 16) =
            *(const float4*)((const char*)Wh + row * 256 + c8 * 16);
        *(float4*)((char*)Bl + row * 272 + c8 * 16) =
            *(const float4*)((const char*)Wlo + row * 256 + c8 * 16);
    }
    __syncthreads();

    const int lane = t & 63, w = t >> 6;
    const int m16 = lane & 15, quad = lane >> 4;
    const int wid = blockIdx.x * 4 + w;
    const int nwaves = gridDim.x * 4;

    float bias[8], scp[8], shp[8];
#pragma unroll
    for (int nt = 0; nt < 8; ++nt) {
        int ch = nt * 16 + m16;
        bias[nt] = b[ch];
        scp[nt] = (prev >= 0) ? g_bn_sc[prev * HIDC + ch] : 1.f;
        shp[nt] = (prev >= 0) ? g_bn_sh[prev * HIDC + ch] : 0.f;
    }
    float sreg[8], qreg[8];
#pragma unroll
    for (int nt = 0; nt < 8; ++nt) { sreg[nt] = 0.f; qreg[nt] = 0.f; }

    for (int tile = wid; tile < NTILES; tile += nwaves) {
        const __hip_bfloat16* ahp = agg_hi + (size_t)(tile * 16 + m16) * HIDC + quad * 8;
        const __hip_bfloat16* alp = agg_lo + (size_t)(tile * 16 + m16) * HIDC + quad * 8;
        floatx4 acc[8];
#pragma unroll
        for (int i = 0; i < 8; ++i) acc[i] = floatx4{0.f, 0.f, 0.f, 0.f};

#pragma unroll
        for (int kk = 0; kk < 4; ++kk) {
            bf16x8 ah = *(const bf16x8*)(ahp + kk * 32);
            bf16x8 al = *(const bf16x8*)(alp + kk * 32);
#pragma unroll
            for (int nt = 0; nt < 8; ++nt) {
                bf16x8 bh = *(const bf16x8*)((const char*)Bh + (nt * 16 + m16) * 272 + (kk * 32 + quad * 8) * 2);
                bf16x8 bl = *(const bf16x8*)((const char*)Bl + (nt * 16 + m16) * 272 + (kk * 32 + quad * 8) * 2);
                acc[nt] = __builtin_amdgcn_mfma_f32_16x16x32_bf16(ah, bh, acc[nt], 0, 0, 0);
                acc[nt] = __builtin_amdgcn_mfma_f32_16x16x32_bf16(al, bh, acc[nt], 0, 0, 0);
                acc[nt] = __builtin_amdgcn_mfma_f32_16x16x32_bf16(ah, bl, acc[nt], 0, 0, 0);
            }
        }
        int node0 = tile * 16 + quad * 4;
#pragma unroll
        for (int nt = 0; nt < 8; ++nt) {
            int ch = nt * 16 + m16;
#pragma unroll
            for (int r = 0; r < 4; ++r) {
                float* hp = h + (size_t)(node0 + r) * HIDC + ch;
                float o = scp[nt] * (*hp) + shp[nt] + acc[nt][r] + bias[nt];
                *hp = o;
                sreg[nt] += o;
                qreg[nt] += o * o;
            }
        }
    }

#pragma unroll
    for (int nt = 0; nt < 8; ++nt) {
        float s = sreg[nt], q = qreg[nt];
        s += __shfl_xor(s, 16); s += __shfl_xor(s, 32);
        q += __shfl_xor(q, 16); q += __shfl_xor(q, 32);
        if (quad == 0) {
            atomicAdd(&red[nt * 16 + m16], s);
            atomicAdd(&red[HIDC + nt * 16 + m16], q);
        }
    }
    __syncthreads();
    atomicAdd(&g_stats[layer * 2 * HIDC + t], red[t]);
}

// ---------------------------------------------------------------------------
// bn_prep: stats -> scale/shift (1 block, 128 threads)
// ---------------------------------------------------------------------------
__global__ void bn_prep_kernel(const float* __restrict__ gamma,
                               const float* __restrict__ beta, int layer)
{
    int c = threadIdx.x;
    if (c >= HIDC) return;
    const float invN = 1.0f / (float)N_NODES;
    float mean = g_stats[layer * 2 * HIDC + c] * invN;
    float var = g_stats[layer * 2 * HIDC + HIDC + c] * invN - mean * mean;
    float s = gamma[layer * HIDC + c] * rsqrtf(var + BN_EPS);
    g_bn_sc[layer * HIDC + c] = s;
    g_bn_sh[layer * HIDC + c] = beta[layer * HIDC + c] - mean * s;
}

// ---------------------------------------------------------------------------
// bn_apply (final output only): h = sc*h + sh
// ---------------------------------------------------------------------------
__global__ __launch_bounds__(256) void bn_apply_kernel(float* __restrict__ h, int layer)
{
    size_t idx = (size_t)blockIdx.x * 256 + threadIdx.x;  // float4 index
    if (idx >= (size_t)N_NODES * (HIDC / 4)) return;
    int cg = (int)(idx & 31);
    float4 sc = ((const float4*)(g_bn_sc + layer * HIDC))[cg];
    float4 sh = ((const float4*)(g_bn_sh + layer * HIDC))[cg];
    float4 v = ((float4*)h)[idx];
    v.x = sc.x * v.x + sh.x;
    v.y = sc.y * v.y + sh.y;
    v.z = sc.z * v.z + sh.z;
    v.w = sc.w * v.w + sh.w;
    ((float4*)h)[idx] = v;
}

// ---------------------------------------------------------------------------
extern "C" void kernel_launch(void* const* d_in, const int* in_sizes, int n_in,
                              void* d_out, int out_size, void* d_ws, size_t ws_size,
                              hipStream_t stream) {
    (void)in_sizes; (void)n_in; (void)out_size; (void)ws_size;
    const float* node_init = (const float*)d_in[0];
    const int*   eidx      = (const int*)d_in[1];   // [2,E] int32
    const float* elen      = (const float*)d_in[2];
    const float* W_in      = (const float*)d_in[3];
    const float* b_in      = (const float*)d_in[4];
    const float* att_k     = (const float*)d_in[5];
    const float* Wl        = (const float*)d_in[6]; // [2,128,128]
    const float* bl        = (const float*)d_in[7]; // [2,128]
    const float* gamma     = (const float*)d_in[8];
    const float* beta      = (const float*)d_in[9];

    float* h = (float*)d_out;                       // [N,128]
    __hip_bfloat16* agg_hi = (__hip_bfloat16*)d_ws; // [N,128] bf16 hi plane
    __hip_bfloat16* agg_lo = agg_hi + (size_t)N_NODES * HIDC; // lo plane

    const int* src = eidx;
    const int* dst = eidx + N_EDGES;

    zero_kernel<<<NB_SCAN, 256, 0, stream>>>();
    hist_kernel<<<(N_EDGES + 255) / 256, 256, 0, stream>>>(dst);
    scan1_kernel<<<NB_SCAN, 256, 0, stream>>>();
    scan2_kernel<<<1, 256, 0, stream>>>();
    scan3_kernel<<<NB_SCAN, 256, 0, stream>>>();
    prep_w_kernel<<<(NLAYERS * 128 * 128 + 255) / 256, 256, 0, stream>>>(W_in, Wl);

    // proj before scatter: ekey(layer 0) is ready, so scatter emits g_ew too.
    proj_mfma_kernel<<<(N_NODES + 63) / 64, 256, 0, stream>>>(node_init, b_in, att_k, h);
    scatter_kernel<<<(N_EDGES + 255) / 256, 256, 0, stream>>>(src, dst, elen);

    for (int l = 0; l < NLAYERS; ++l) {
        if (l > 0) {
            key_kernel<<<(N_NODES / 2 + 3) / 4, 256, 0, stream>>>(h, att_k, l - 1);
            wt_kernel<<<(N_EDGES + 255) / 256, 256, 0, stream>>>();
        }
        edge_csr_kernel<<<(N_NODES + 7) / 8, 256, 0, stream>>>(h, agg_hi, agg_lo, l - 1);
        layer_gemm_kernel<<<512, 256, 0, stream>>>(h, agg_hi, agg_lo, bl + (size_t)l * HIDC, l, l - 1);
        bn_prep_kernel<<<1, 128, 0, stream>>>(gamma, beta, l);
    }
    bn_apply_kernel<<<(N_NODES * (HIDC / 4) + 255) / 256, 256, 0, stream>>>(h, NLAYERS - 1);
}